// Round 1
// baseline (567.338 us; speedup 1.0000x reference)
//
#include <hip/hip_runtime.h>

// BiLSTM: L1 (H=50) both dirs + L2 forward full scan + L2 backward single step + heads.
// Strategy: persistent-VGPR fp16 MFMA weights per block, NB=16 batches/block,
// fp32 gates/c, fp16 h/x through LDS in MFMA-B-fragment-native layout.

typedef unsigned short u16;
typedef unsigned int u32;
typedef float f32x4 __attribute__((ext_vector_type(4)));
typedef _Float16 f16x8 __attribute__((ext_vector_type(8)));
typedef short s16x8 __attribute__((ext_vector_type(8)));

#if __has_builtin(__builtin_amdgcn_mfma_f32_16x16x32_f16)
#define USE_F16 1
#else
#define USE_F16 0
#endif

#define B1 1024
#define TT 128

__device__ __forceinline__ u16 to_h(float x) {
#if USE_F16
    _Float16 h = (_Float16)x;
    return __builtin_bit_cast(u16, h);
#else
    u32 u = __builtin_bit_cast(u32, x);
    u32 r = u + 0x7FFFu + ((u >> 16) & 1u);
    return (u16)(r >> 16);
#endif
}
__device__ __forceinline__ float from_h(u16 s) {
#if USE_F16
    return (float)__builtin_bit_cast(_Float16, s);
#else
    u32 u = ((u32)s) << 16;
    return __builtin_bit_cast(float, u);
#endif
}

__device__ __forceinline__ f32x4 mfma16(uint4 a, uint4 b, f32x4 c) {
#if USE_F16
    return __builtin_amdgcn_mfma_f32_16x16x32_f16(
        __builtin_bit_cast(f16x8, a), __builtin_bit_cast(f16x8, b), c, 0, 0, 0);
#else
    return __builtin_amdgcn_mfma_f32_16x16x32_bf16(
        __builtin_bit_cast(s16x8, a), __builtin_bit_cast(s16x8, b), c, 0, 0, 0);
#endif
}

#define LOG2E 1.4426950408889634f
__device__ __forceinline__ float fast_rcp(float x) { return __builtin_amdgcn_rcpf(x); }
__device__ __forceinline__ float sigm(float x) {
    return fast_rcp(1.f + __builtin_amdgcn_exp2f(-LOG2E * x));
}
__device__ __forceinline__ float tanh_(float x) {
    return 1.f - 2.f * fast_rcp(1.f + __builtin_amdgcn_exp2f(2.f * LOG2E * x));
}

// Pack weights [Wih | Whh | 0] into MFMA A-fragment order:
// frag[(tile*KT+kt)*64 + lane] = 4 dwords = 8 fp16 for k = kt*32 + (lane>>4)*8 + j.
__global__ void prep_frag(const float* __restrict__ Wih, const float* __restrict__ Whh,
                          uint4* __restrict__ dst, int M, int K1, int K2, int kt_shift)
{
    int bid = blockIdx.x;
    int l = threadIdx.x;
    int ktmask = (1 << kt_shift) - 1;
    int m = bid >> kt_shift;
    int kt = bid & ktmask;
    int r = m * 16 + (l & 15);
    u32 dw[4];
    #pragma unroll
    for (int d = 0; d < 4; ++d) {
        u16 hh[2];
        #pragma unroll
        for (int q = 0; q < 2; ++q) {
            int j = d * 2 + q;
            int k = kt * 32 + (l >> 4) * 8 + j;
            float val = 0.f;
            if (r < M) {
                if (k < K1) val = Wih[r * K1 + k];
                else if (k < K1 + K2) val = Whh[r * K2 + (k - K1)];
            }
            hh[q] = to_h(val);
        }
        dw[d] = (u32)hh[0] | ((u32)hh[1] << 16);
    }
    uint4 o; o.x = dw[0]; o.y = dw[1]; o.z = dw[2]; o.w = dw[3];
    dst[bid * 64 + l] = o;
}

// Transpose W [G][K] -> WtT [K][G]  (for coalesced l2b reads)
__global__ void prep_transT(const float* __restrict__ W, float* __restrict__ WtT, int K, int G)
{
    int idx = blockIdx.x * 256 + threadIdx.x;
    if (idx < K * G) {
        int k = idx / G, g = idx - k * G;
        WtT[idx] = W[g * K + k];
    }
}

// Layer 1 scan, one dir per blockIdx.y, 16 batches per block. M=200 gates -> 16 tiles (pad),
// K=64 (x at k=0, h at k=1..50, pad). 256 threads = 4 waves, 4 tiles/wave.
__global__ __launch_bounds__(256, 2) void l1_scan(
    const float* __restrict__ x,
    const uint4* __restrict__ fragF, const uint4* __restrict__ fragB,
    const float* __restrict__ biasF, const float* __restrict__ biasB,
    u16* __restrict__ out1)   // [T][100][1024] fp16 bits
{
    const int tid = threadIdx.x;
    const int lane = tid & 63;
    const int w = tid >> 6;
    const int b0 = blockIdx.x * 16;
    const int dir = blockIdx.y;
    const uint4* frag = dir ? fragB : fragF;
    const float* bias = dir ? biasB : biasF;

    __shared__ alignas(16) u16 v[2 * 64 * 8];       // [kt][lane][e]
    __shared__ alignas(16) float gbuf[16][260];     // [b][gate]
    __shared__ float c_s[50][16];
    __shared__ float x_s[16][128];

    uint4 af[4][2];
    #pragma unroll
    for (int i = 0; i < 4; ++i) {
        int tile = w + 4 * i;
        #pragma unroll
        for (int kt = 0; kt < 2; ++kt)
            af[i][kt] = frag[(tile * 2 + kt) * 64 + lane];
    }
    for (int idx = tid; idx < 512; idx += 256) ((u32*)v)[idx] = 0u;
    for (int idx = tid; idx < 800; idx += 256) ((float*)c_s)[idx] = 0.f;
    for (int idx = tid; idx < 2048; idx += 256) {
        int b = idx >> 7, tq = idx & 127;
        x_s[b][tq] = x[(size_t)(b0 + b) * TT + tq];
    }
    if (tid < 16) v[tid * 8] = to_h(x[(size_t)(b0 + tid) * TT + (dir ? TT - 1 : 0)]);
    __syncthreads();

    for (int t = 0; t < TT; ++t) {
        const int tt = dir ? (TT - 1 - t) : t;
        uint4 bfu[2];
        #pragma unroll
        for (int kt = 0; kt < 2; ++kt)
            bfu[kt] = *(const uint4*)&v[(kt * 64 + lane) * 8];
        #pragma unroll
        for (int i = 0; i < 4; ++i) {
            f32x4 acc = {0.f, 0.f, 0.f, 0.f};
            #pragma unroll
            for (int kt = 0; kt < 2; ++kt)
                acc = mfma16(af[i][kt], bfu[kt], acc);
            int tile = w + 4 * i;
            *(f32x4*)&gbuf[lane & 15][tile * 16 + (lane >> 4) * 4] = acc;
        }
        __syncthreads();
        for (int idx = tid; idx < 800; idx += 256) {
            int j = idx >> 4, b = idx & 15;
            float ig = gbuf[b][j]       + bias[j];
            float fg = gbuf[b][j + 50]  + bias[j + 50];
            float gg = gbuf[b][j + 100] + bias[j + 100];
            float og = gbuf[b][j + 150] + bias[j + 150];
            float cn = sigm(fg) * c_s[j][b] + sigm(ig) * tanh_(gg);
            float hn = sigm(og) * tanh_(cn);
            c_s[j][b] = cn;
            u16 hb = to_h(hn);
            out1[((size_t)tt * 100 + dir * 50 + j) * B1 + b0 + b] = hb;
            int k = 1 + j;
            int kt = k >> 5, g = (k & 31) >> 3, e = k & 7;
            v[(kt * 64 + g * 16 + b) * 8 + e] = hb;
        }
        if (tid < 16 && t < TT - 1)
            v[tid * 8] = to_h(x_s[tid][dir ? TT - 2 - t : t + 1]);
        __syncthreads();
    }
}

// Layer 2 forward scan. M=600 gates -> 40 tiles (pad), K=256 (x:0..99, h:100..249, pad).
// 512 threads = 8 waves, 5 tiles/wave, 16 batches/block, grid=64.
__global__ __launch_bounds__(512, 2) void l2f_scan(
    const uint4* __restrict__ frag,
    const u16* __restrict__ out1,
    const float* __restrict__ bias,
    float* __restrict__ net)          // [1024][300], writes [:, 0:150]
{
    const int tid = threadIdx.x;
    const int lane = tid & 63;
    const int w = tid >> 6;
    const int b0 = blockIdx.x * 16;

    __shared__ alignas(16) u16 v[8 * 64 * 8];       // [kt][lane][e]
    __shared__ alignas(16) float gbuf[16][644];
    __shared__ float c_s[150][16];

    uint4 af[5][8];
    #pragma unroll
    for (int i = 0; i < 5; ++i) {
        int tile = w + 8 * i;
        #pragma unroll
        for (int kt = 0; kt < 8; ++kt)
            af[i][kt] = frag[(tile * 8 + kt) * 64 + lane];
    }
    for (int idx = tid; idx < 2048; idx += 512) ((u32*)v)[idx] = 0u;
    for (int idx = tid; idx < 2400; idx += 512) ((float*)c_s)[idx] = 0.f;
    for (int idx = tid; idx < 400; idx += 512) {
        int k2 = idx >> 2, p = idx & 3;
        ushort4 d = *(const ushort4*)&out1[(size_t)(0 * 100 + k2) * B1 + b0 + p * 4];
        int kt = k2 >> 5, g = (k2 & 31) >> 3, e = k2 & 7;
        int base = (kt * 64 + g * 16) * 8 + e;
        v[base + (p * 4 + 0) * 8] = d.x;
        v[base + (p * 4 + 1) * 8] = d.y;
        v[base + (p * 4 + 2) * 8] = d.z;
        v[base + (p * 4 + 3) * 8] = d.w;
    }
    __syncthreads();

    for (int t = 0; t < TT; ++t) {
        uint4 bfu[8];
        #pragma unroll
        for (int kt = 0; kt < 8; ++kt)
            bfu[kt] = *(const uint4*)&v[(kt * 64 + lane) * 8];
        f32x4 acc[5];
        #pragma unroll
        for (int i = 0; i < 5; ++i) acc[i] = (f32x4){0.f, 0.f, 0.f, 0.f};
        #pragma unroll
        for (int kt = 0; kt < 8; ++kt) {
            #pragma unroll
            for (int i = 0; i < 5; ++i)
                acc[i] = mfma16(af[i][kt], bfu[kt], acc[i]);
        }
        #pragma unroll
        for (int i = 0; i < 5; ++i) {
            int tile = w + 8 * i;
            *(f32x4*)&gbuf[lane & 15][tile * 16 + (lane >> 4) * 4] = acc[i];
        }
        __syncthreads();

        for (int idx = tid; idx < 2400; idx += 512) {
            int j = idx >> 4, b = idx & 15;
            float ig = gbuf[b][j]       + bias[j];
            float fg = gbuf[b][j + 150] + bias[j + 150];
            float gg = gbuf[b][j + 300] + bias[j + 300];
            float og = gbuf[b][j + 450] + bias[j + 450];
            float cn = sigm(fg) * c_s[j][b] + sigm(ig) * tanh_(gg);
            float hn = sigm(og) * tanh_(cn);
            c_s[j][b] = cn;
            if (t == TT - 1) net[(size_t)(b0 + b) * 300 + j] = hn;
            int k = 100 + j;
            int kt = k >> 5, g = (k & 31) >> 3, e = k & 7;
            v[(kt * 64 + g * 16 + b) * 8 + e] = to_h(hn);
        }
        if (t < TT - 1) {
            int tn = t + 1;
            for (int idx = tid; idx < 400; idx += 512) {
                int k2 = idx >> 2, p = idx & 3;
                ushort4 d = *(const ushort4*)&out1[((size_t)tn * 100 + k2) * B1 + b0 + p * 4];
                int kt = k2 >> 5, g = (k2 & 31) >> 3, e = k2 & 7;
                int base = (kt * 64 + g * 16) * 8 + e;
                v[base + (p * 4 + 0) * 8] = d.x;
                v[base + (p * 4 + 1) * 8] = d.y;
                v[base + (p * 4 + 2) * 8] = d.z;
                v[base + (p * 4 + 3) * 8] = d.w;
            }
        }
        __syncthreads();
    }
}

// Layer 2 backward = single step from zero state: g = Wih_b @ out1[:,T-1] + b_b (Whh drops out).
__global__ __launch_bounds__(640, 1) void l2b_step(
    const u16* __restrict__ out1, const float* __restrict__ WtT,
    const float* __restrict__ bias, float* __restrict__ net)   // writes [:, 150:300]
{
    const int tid = threadIdx.x;
    const int b0 = blockIdx.x * 16;
    __shared__ alignas(16) float x_s[100][16];
    __shared__ alignas(16) float gbuf[16][644];
    for (int idx = tid; idx < 1600; idx += 640) {
        int k2 = idx >> 4, b = idx & 15;
        x_s[k2][b] = from_h(out1[((size_t)(TT - 1) * 100 + k2) * B1 + b0 + b]);
    }
    __syncthreads();
    if (tid < 600) {
        int g = tid;
        float acc[16];
        #pragma unroll
        for (int b = 0; b < 16; ++b) acc[b] = 0.f;
        for (int k = 0; k < 100; ++k) {
            float wv = WtT[k * 600 + g];
            float4 xa = *(const float4*)&x_s[k][0];
            float4 xb = *(const float4*)&x_s[k][4];
            float4 xc = *(const float4*)&x_s[k][8];
            float4 xd = *(const float4*)&x_s[k][12];
            acc[0] = fmaf(wv, xa.x, acc[0]);  acc[1] = fmaf(wv, xa.y, acc[1]);
            acc[2] = fmaf(wv, xa.z, acc[2]);  acc[3] = fmaf(wv, xa.w, acc[3]);
            acc[4] = fmaf(wv, xb.x, acc[4]);  acc[5] = fmaf(wv, xb.y, acc[5]);
            acc[6] = fmaf(wv, xb.z, acc[6]);  acc[7] = fmaf(wv, xb.w, acc[7]);
            acc[8] = fmaf(wv, xc.x, acc[8]);  acc[9] = fmaf(wv, xc.y, acc[9]);
            acc[10] = fmaf(wv, xc.z, acc[10]); acc[11] = fmaf(wv, xc.w, acc[11]);
            acc[12] = fmaf(wv, xd.x, acc[12]); acc[13] = fmaf(wv, xd.y, acc[13]);
            acc[14] = fmaf(wv, xd.z, acc[14]); acc[15] = fmaf(wv, xd.w, acc[15]);
        }
        #pragma unroll
        for (int b = 0; b < 16; ++b) gbuf[b][g] = acc[b];
    }
    __syncthreads();
    for (int idx = tid; idx < 2400; idx += 640) {
        int j = idx >> 4, b = idx & 15;
        float ig = gbuf[b][j]       + bias[j];
        float gg = gbuf[b][j + 300] + bias[j + 300];
        float og = gbuf[b][j + 450] + bias[j + 450];
        float cn = sigm(ig) * tanh_(gg);           // c0 = 0 -> forget term vanishes
        float hn = sigm(og) * tanh_(cn);
        net[(size_t)(b0 + b) * 300 + 150 + j] = hn;
    }
}

// waveform_feat + pef + pef_logits + feat
__global__ void head1(const float* __restrict__ net, const float* __restrict__ rrs,
                      const float* __restrict__ headW, const float* __restrict__ headb,
                      const float* __restrict__ p1W, const float* __restrict__ p1b,
                      const float* __restrict__ p2W, const float* __restrict__ p2b,
                      float* __restrict__ out)
{
    int gid = blockIdx.x * 256 + threadIdx.x;     // 4096
    int b = gid >> 2, og = gid & 3;
    float acc[5];
    #pragma unroll
    for (int o2 = 0; o2 < 5; ++o2) acc[o2] = headb[og * 5 + o2];
    const float* nb = net + (size_t)b * 300;
    for (int k = 0; k < 300; ++k) {
        float nv = nb[k];
        #pragma unroll
        for (int o2 = 0; o2 < 5; ++o2)
            acc[o2] = fmaf(headW[(og * 5 + o2) * 300 + k], nv, acc[o2]);
    }
    #pragma unroll
    for (int o2 = 0; o2 < 5; ++o2) {
        int o = og * 5 + o2;
        float vv = acc[o2] > 0.f ? acc[o2] : 0.3f * acc[o2];
        out[b * 20 + o] = vv;                  // waveform_feat
        out[22528 + b * 30 + o] = vv;          // feat[:, :20]
    }
    if (og == 0) {
        float p[10];
        #pragma unroll
        for (int r = 0; r < 10; ++r) {
            float a = p1b[r];
            #pragma unroll
            for (int q = 0; q < 4; ++q) a = fmaf(p1W[r * 4 + q], rrs[b * 4 + q], a);
            p[r] = a > 0.f ? a : 0.3f * a;
            out[22528 + b * 30 + 20 + r] = p[r];   // feat[:, 20:30]
        }
        #pragma unroll
        for (int s = 0; s < 2; ++s) {
            float a = p2b[s];
            #pragma unroll
            for (int r = 0; r < 10; ++r) a = fmaf(p2W[s * 10 + r], p[r], a);
            out[20480 + b * 2 + s] = a;            // pef_logits
        }
    }
}

// logits = feat @ fc_W.T + fc_b  (reads feat from d_out, separate launch for ordering)
__global__ void head2(const float* __restrict__ fcW, const float* __restrict__ fcb,
                      float* __restrict__ out)
{
    int b = blockIdx.x * 256 + threadIdx.x;   // 1024
    const float* feat = out + 22528 + b * 30;
    float f[30];
    #pragma unroll
    for (int k = 0; k < 30; ++k) f[k] = feat[k];
    #pragma unroll
    for (int s = 0; s < 4; ++s) {
        float a = fcb[s];
        #pragma unroll
        for (int k = 0; k < 30; ++k) a = fmaf(fcW[s * 30 + k], f[k], a);
        out[53248 + b * 4 + s] = a;
    }
}

extern "C" void kernel_launch(void* const* d_in, const int* in_sizes, int n_in,
                              void* d_out, int out_size, void* d_ws, size_t ws_size,
                              hipStream_t stream)
{
    const float* x     = (const float*)d_in[0];
    const float* rrs   = (const float*)d_in[1];
    const float* W1ihF = (const float*)d_in[2];
    const float* W1hhF = (const float*)d_in[3];
    const float* b1F   = (const float*)d_in[4];
    const float* W1ihB = (const float*)d_in[5];
    const float* W1hhB = (const float*)d_in[6];
    const float* b1B   = (const float*)d_in[7];
    const float* W2ihF = (const float*)d_in[8];
    const float* W2hhF = (const float*)d_in[9];
    const float* b2F   = (const float*)d_in[10];
    const float* W2ihB = (const float*)d_in[11];
    // d_in[12] (l2_Whh_b) unused: backward scan output at t=T-1 starts from h0=0.
    const float* b2B   = (const float*)d_in[13];
    const float* headW = (const float*)d_in[14];
    const float* headb = (const float*)d_in[15];
    const float* p1W   = (const float*)d_in[16];
    const float* p1b   = (const float*)d_in[17];
    const float* p2W   = (const float*)d_in[18];
    const float* p2b   = (const float*)d_in[19];
    const float* fcW   = (const float*)d_in[20];
    const float* fcb   = (const float*)d_in[21];
    float* out = (float*)d_out;

    char* ws = (char*)d_ws;
    uint4* frag1f = (uint4*)(ws + 0);          //  32 KB  (16 tiles x 2 kt x 64 x 16B)
    uint4* frag1b = (uint4*)(ws + 32768);      //  32 KB
    uint4* frag2f = (uint4*)(ws + 65536);      // 320 KB  (40 tiles x 8 kt x 64 x 16B)
    float* WtT    = (float*)(ws + 393216);     // 240 KB  (Wih2_b transposed [100][600])
    u16*   out1   = (u16*)(ws + 655360);       //  25 MB  ([128][100][1024] fp16)
    float* net    = (float*)(ws + 655360 + 26214400);  // 1.2 MB ([1024][300])
    (void)ws_size; (void)in_sizes; (void)n_in; (void)out_size;

    prep_frag<<<32, 64, 0, stream>>>(W1ihF, W1hhF, frag1f, 200, 1, 50, 1);
    prep_frag<<<32, 64, 0, stream>>>(W1ihB, W1hhB, frag1b, 200, 1, 50, 1);
    prep_frag<<<320, 64, 0, stream>>>(W2ihF, W2hhF, frag2f, 600, 100, 150, 3);
    prep_transT<<<(60000 + 255) / 256, 256, 0, stream>>>(W2ihB, WtT, 100, 600);
    l1_scan<<<dim3(64, 2), 256, 0, stream>>>(x, frag1f, frag1b, b1F, b1B, out1);
    l2f_scan<<<64, 512, 0, stream>>>(frag2f, out1, b2F, net);
    l2b_step<<<64, 640, 0, stream>>>(out1, WtT, b2B, net);
    head1<<<16, 256, 0, stream>>>(net, rrs, headW, headb, p1W, p1b, p2W, p2b, out);
    head2<<<4, 256, 0, stream>>>(fcW, fcb, out);
}

// Round 3
// 322.234 us; speedup vs baseline: 1.7606x; 1.7606x over previous
//
#include <hip/hip_runtime.h>

// BiLSTM on MI355X. Structure:
//  - l1_scan: H=50 bidir LSTM, gates fully in-register via permuted MFMA weight
//    packing; writes out1 directly in MFMA B-fragment layout (fp16).
//  - l2f_scan: H=150 forward scan; x-fragments streamed from global (prefetched
//    1 step ahead), h recurrent through double-buffered LDS; 1 barrier/step.
//  - l2b: backward scan's last output = single step from zero state (Whh drops).
//  - bias folded into an extra K-column against a constant-1.0 B row.
// FIX vs prev round: __syncthreads() between LDS zero-init and the special-slot
// writes (bias row / x-part) — wave 0 raced ahead of other waves' zeroing
// iterations and the late zeros clobbered the bias column.

typedef unsigned short u16;
typedef unsigned int u32;
typedef float f32x4 __attribute__((ext_vector_type(4)));
typedef _Float16 f16x8 __attribute__((ext_vector_type(8)));
typedef short s16x8 __attribute__((ext_vector_type(8)));

#if __has_builtin(__builtin_amdgcn_mfma_f32_16x16x32_f16)
#define USE_F16 1
#else
#define USE_F16 0
#endif

#define B1 1024
#define TT 128

__device__ __forceinline__ u16 to_h(float x) {
#if USE_F16
    _Float16 h = (_Float16)x;
    return __builtin_bit_cast(u16, h);
#else
    u32 u = __builtin_bit_cast(u32, x);
    u32 r = u + 0x7FFFu + ((u >> 16) & 1u);
    return (u16)(r >> 16);
#endif
}
__device__ __forceinline__ float from_h(u16 s) {
#if USE_F16
    return (float)__builtin_bit_cast(_Float16, s);
#else
    u32 u = ((u32)s) << 16;
    return __builtin_bit_cast(float, u);
#endif
}

__device__ __forceinline__ f32x4 mfma16(uint4 a, uint4 b, f32x4 c) {
#if USE_F16
    return __builtin_amdgcn_mfma_f32_16x16x32_f16(
        __builtin_bit_cast(f16x8, a), __builtin_bit_cast(f16x8, b), c, 0, 0, 0);
#else
    return __builtin_amdgcn_mfma_f32_16x16x32_bf16(
        __builtin_bit_cast(s16x8, a), __builtin_bit_cast(s16x8, b), c, 0, 0, 0);
#endif
}

#define LOG2E 1.4426950408889634f
__device__ __forceinline__ float sigm(float x) {
    return __builtin_amdgcn_rcpf(1.f + __builtin_amdgcn_exp2f(-LOG2E * x));
}
__device__ __forceinline__ float tanh_(float x) {
    return 1.f - 2.f * __builtin_amdgcn_rcpf(1.f + __builtin_amdgcn_exp2f(2.f * LOG2E * x));
}

// ---------------------------------------------------------------------------
// Weight prep: pack [Wih | Whh | bias-col | 0] into MFMA A-fragments with the
// gate-permutation: row m = tile*16 + q*4 + tau, tile = w + NW*p,
// group jj = (w*4+q)*NP + p, original row = tau*GR + jj.
// Consumer thread (wave w, lane q*16+b) then holds gates (i,f,g,o) of group
// jj in acc[p][0..3] -> gate nonlinearity fully in-register.
__global__ void prep_frag(const float* __restrict__ Wih, const float* __restrict__ Whh,
                          const float* __restrict__ bias, uint4* __restrict__ dst,
                          int GR, int NW, int NP, int KT,
                          int x_off, int x_len, int h_off, int h_len, int bias_k)
{
    int bid = blockIdx.x;
    int l = threadIdx.x;
    int tile = bid / KT, kt = bid - tile * KT;
    int ml = l & 15;
    int qq = ml >> 2, tau = ml & 3;
    int w = tile % NW, p = tile / NW;
    int jj = (w * 4 + qq) * NP + p;
    bool valid = jj < GR;
    int row = tau * GR + jj;
    u32 dw[4];
    #pragma unroll
    for (int d = 0; d < 4; ++d) {
        u16 hh[2];
        #pragma unroll
        for (int s = 0; s < 2; ++s) {
            int j = d * 2 + s;
            int k = kt * 32 + (l >> 4) * 8 + j;
            float val = 0.f;
            if (valid) {
                if (k >= x_off && k < x_off + x_len) val = Wih[row * x_len + (k - x_off)];
                else if (k >= h_off && k < h_off + h_len) val = Whh[row * h_len + (k - h_off)];
                else if (k == bias_k) val = bias[row];
            }
            hh[s] = to_h(val);
        }
        dw[d] = (u32)hh[0] | ((u32)hh[1] << 16);
    }
    uint4 o; o.x = dw[0]; o.y = dw[1]; o.z = dw[2]; o.w = dw[3];
    dst[bid * 64 + l] = o;
}

// Transpose W [G][K] -> WtT [K][G]  (for coalesced l2b reads)
__global__ void prep_transT(const float* __restrict__ W, float* __restrict__ WtT, int K, int G)
{
    int idx = blockIdx.x * 256 + threadIdx.x;
    if (idx < K * G) {
        int k = idx / G, g = idx - k * G;
        WtT[idx] = W[g * K + k];
    }
}

// ---------------------------------------------------------------------------
// Layer 1: K=64 (x at k=0, h at k=1..50, bias at k=63). 256 thr = 4 waves,
// 4 tiles/wave (tile = w+4p), groups jj = w*16+q*4+p (valid < 50).
// out1f layout: u16 fragment tensor [t][blk][ktx(4)][lane(64)][e(8)].
__global__ __launch_bounds__(256, 4) void l1_scan(
    const float* __restrict__ x, const uint4* __restrict__ fragF,
    const uint4* __restrict__ fragB, u16* __restrict__ out1f)
{
    const int tid = threadIdx.x;
    const int lane = tid & 63;
    const int w = tid >> 6;
    const int q = lane >> 4;
    const int b = lane & 15;
    const int blk = blockIdx.x;
    const int dir = blockIdx.y;
    const uint4* frag = dir ? fragB : fragF;

    __shared__ u16 v[2][1024];        // [buf][kt(2)*64 lanes*8 e]
    __shared__ float x_s[128][17];    // padded: conflict-free col reads

    uint4 af[4][2];
    #pragma unroll
    for (int i = 0; i < 4; ++i)
        #pragma unroll
        for (int kt = 0; kt < 2; ++kt)
            af[i][kt] = frag[((w + 4 * i) * 2 + kt) * 64 + lane];

    const int b0 = blk * 16;
    for (int idx = tid; idx < 1024; idx += 256) ((u32*)v)[idx] = 0u;
    for (int idx = tid; idx < 2048; idx += 256) {
        int bb = idx >> 7, t = idx & 127;
        x_s[t][bb] = x[(size_t)(b0 + bb) * TT + t];
    }
    __syncthreads();                  // zero-init complete before special slots
    const u16 oneh = to_h(1.0f);
    if (tid < 16) {
        v[0][(112 + tid) * 8 + 7] = oneh;             // bias row k=63, both bufs
        v[1][(112 + tid) * 8 + 7] = oneh;
        v[0][tid * 8] = to_h(x[(size_t)(b0 + tid) * TT + (dir ? TT - 1 : 0)]);
    }
    const int jjb = w * 16 + q * 4;
    int vslot[4]; size_t eb[4];
    #pragma unroll
    for (int p = 0; p < 4; ++p) {
        int jj = jjb + p;
        int k = 1 + jj;
        vslot[p] = ((k >> 5) * 64 + ((k & 31) >> 3) * 16 + b) * 8 + (k & 7);
        int k2 = dir * 50 + jj;
        eb[p] = (((size_t)blk * 4 + (k2 >> 5)) * 64 + ((k2 & 31) >> 3) * 16 + b) * 8 + (k2 & 7);
    }
    float c[4] = {0.f, 0.f, 0.f, 0.f};
    __syncthreads();

#define L1_STEP(T, CUR) { \
    uint4 bf0 = *(const uint4*)&v[CUR][lane * 8]; \
    uint4 bf1 = *(const uint4*)&v[CUR][(64 + lane) * 8]; \
    f32x4 acc[4]; \
    _Pragma("unroll") for (int i = 0; i < 4; ++i) acc[i] = (f32x4){0.f, 0.f, 0.f, 0.f}; \
    _Pragma("unroll") for (int i = 0; i < 4; ++i) acc[i] = mfma16(af[i][0], bf0, acc[i]); \
    _Pragma("unroll") for (int i = 0; i < 4; ++i) acc[i] = mfma16(af[i][1], bf1, acc[i]); \
    const int tt = dir ? 127 - (T) : (T); \
    _Pragma("unroll") for (int p = 0; p < 4; ++p) { \
        if (jjb + p < 50) { \
            float ig = acc[p][0], fg = acc[p][1], gg = acc[p][2], og = acc[p][3]; \
            float cn = sigm(fg) * c[p] + sigm(ig) * tanh_(gg); \
            float hn = sigm(og) * tanh_(cn); \
            c[p] = cn; \
            u16 hb = to_h(hn); \
            out1f[eb[p] + (size_t)tt * 131072] = hb; \
            v[1 - (CUR)][vslot[p]] = hb; \
        } \
    } \
    if (tid < 16 && (T) < 127) \
        v[1 - (CUR)][tid * 8] = to_h(x_s[dir ? 126 - (T) : (T) + 1][tid]); \
    __syncthreads(); }

    for (int t2 = 0; t2 < TT; t2 += 2) {
        L1_STEP(t2, 0)
        L1_STEP(t2 + 1, 1)
    }
#undef L1_STEP
}

// ---------------------------------------------------------------------------
// Layer 2 forward: K=256 (x k=0..99, h k=100..249, bias k=255). 512 thr = 8
// waves, 5 tiles/wave (tile = w+8p), groups jj = w*20+q*5+p (valid < 150).
// x-fragments (kt 0..2) MFMA'd straight from prefetched registers; kt3 merged
// (x k=96..99 from pf regs -> LDS, h k=100..127 from gate writers); h double-
// buffered in LDS. ONE barrier per step.
__global__ __launch_bounds__(512, 2) void l2f_scan(
    const uint4* __restrict__ frag, const u16* __restrict__ out1f,
    float* __restrict__ net)
{
    const int tid = threadIdx.x;
    const int lane = tid & 63;
    const int w = tid >> 6;
    const int q = lane >> 4;
    const int b = lane & 15;
    const int blk = blockIdx.x;
    const int b0 = blk * 16;
    const uint4* o4 = (const uint4*)out1f;

    __shared__ u16 v[2][4096];        // [buf][kt(8)*64 lanes*8 e]

    uint4 af[5][8];
    #pragma unroll
    for (int i = 0; i < 5; ++i)
        #pragma unroll
        for (int kt = 0; kt < 8; ++kt)
            af[i][kt] = frag[((w + 8 * i) * 8 + kt) * 64 + lane];

    for (int idx = tid; idx < 4096; idx += 512) ((u32*)v)[idx] = 0u;

    uint4 pfA[4], pfB[4];
    #pragma unroll
    for (int ktx = 0; ktx < 4; ++ktx)
        pfA[ktx] = o4[((size_t)blk * 4 + ktx) * 64 + lane];

    __syncthreads();                  // zero-init complete before special slots
    const u16 oneh = to_h(1.0f);
    if (tid < 16) {                   // bias row k=255, both bufs
        v[0][(496 + tid) * 8 + 7] = oneh;
        v[1][(496 + tid) * 8 + 7] = oneh;
    }
    if (w == 0 && lane < 16) {        // x(0) k=96..99 into v[0]
        uint2 xv; xv.x = pfA[3].x; xv.y = pfA[3].y;
        *(uint2*)&v[0][(192 + lane) * 8] = xv;
    }

    const int jjb = w * 20 + q * 5;
    int vslot[5];
    #pragma unroll
    for (int p = 0; p < 5; ++p) {
        int k = 100 + jjb + p;
        vslot[p] = ((k >> 5) * 64 + ((k & 31) >> 3) * 16 + b) * 8 + (k & 7);
    }
    float c[5] = {0.f, 0.f, 0.f, 0.f, 0.f};
    __syncthreads();

#define L2F_STEP(T, CUR, PFC, PFN) { \
    const int tn = ((T) < 127) ? (T) + 1 : 127; \
    _Pragma("unroll") for (int ktx = 0; ktx < 4; ++ktx) \
        PFN[ktx] = o4[(((size_t)tn * 64 + blk) * 4 + ktx) * 64 + lane]; \
    uint4 bfu[5]; \
    _Pragma("unroll") for (int kh = 0; kh < 5; ++kh) \
        bfu[kh] = *(const uint4*)&v[CUR][((kh + 3) * 64 + lane) * 8]; \
    f32x4 acc[5]; \
    _Pragma("unroll") for (int i = 0; i < 5; ++i) acc[i] = (f32x4){0.f, 0.f, 0.f, 0.f}; \
    _Pragma("unroll") for (int kt = 0; kt < 3; ++kt) { \
        _Pragma("unroll") for (int i = 0; i < 5; ++i) \
            acc[i] = mfma16(af[i][kt], PFC[kt], acc[i]); } \
    _Pragma("unroll") for (int kh = 0; kh < 5; ++kh) { \
        _Pragma("unroll") for (int i = 0; i < 5; ++i) \
            acc[i] = mfma16(af[i][kh + 3], bfu[kh], acc[i]); } \
    _Pragma("unroll") for (int p = 0; p < 5; ++p) { \
        float ig = acc[p][0], fg = acc[p][1], gg = acc[p][2], og = acc[p][3]; \
        float cn = sigm(fg) * c[p] + sigm(ig) * tanh_(gg); \
        float hn = sigm(og) * tanh_(cn); \
        c[p] = cn; \
        if (jjb + p < 150) { \
            v[1 - (CUR)][vslot[p]] = to_h(hn); \
            if ((T) == 127) net[(size_t)(b0 + b) * 300 + jjb + p] = hn; \
        } \
    } \
    if (w == 0 && lane < 16) { \
        uint2 xv; xv.x = PFN[3].x; xv.y = PFN[3].y; \
        *(uint2*)&v[1 - (CUR)][(192 + lane) * 8] = xv; \
    } \
    __syncthreads(); }

    for (int t2 = 0; t2 < TT; t2 += 2) {
        L2F_STEP(t2, 0, pfA, pfB)
        L2F_STEP(t2 + 1, 1, pfB, pfA)
    }
#undef L2F_STEP
}

// ---------------------------------------------------------------------------
// Layer 2 backward = single step from zero state (Whh_b drops out).
__global__ __launch_bounds__(640, 1) void l2b_step(
    const u16* __restrict__ out1f, const float* __restrict__ WtT,
    const float* __restrict__ bias, float* __restrict__ net)   // writes [:, 150:300]
{
    const int tid = threadIdx.x;
    const int blk = blockIdx.x;
    const int b0 = blk * 16;
    __shared__ alignas(16) float x_s[100][16];
    __shared__ alignas(16) float gbuf[16][644];
    for (int idx = tid; idx < 1600; idx += 640) {
        int k2 = idx >> 4, bb = idx & 15;
        x_s[k2][bb] = from_h(out1f[((((size_t)127 * 64 + blk) * 4 + (k2 >> 5)) * 64
                                    + ((k2 & 31) >> 3) * 16 + bb) * 8 + (k2 & 7)]);
    }
    __syncthreads();
    if (tid < 600) {
        int g = tid;
        float acc[16];
        #pragma unroll
        for (int bb = 0; bb < 16; ++bb) acc[bb] = 0.f;
        for (int k = 0; k < 100; ++k) {
            float wv = WtT[k * 600 + g];
            float4 xa = *(const float4*)&x_s[k][0];
            float4 xb = *(const float4*)&x_s[k][4];
            float4 xc = *(const float4*)&x_s[k][8];
            float4 xd = *(const float4*)&x_s[k][12];
            acc[0] = fmaf(wv, xa.x, acc[0]);  acc[1] = fmaf(wv, xa.y, acc[1]);
            acc[2] = fmaf(wv, xa.z, acc[2]);  acc[3] = fmaf(wv, xa.w, acc[3]);
            acc[4] = fmaf(wv, xb.x, acc[4]);  acc[5] = fmaf(wv, xb.y, acc[5]);
            acc[6] = fmaf(wv, xb.z, acc[6]);  acc[7] = fmaf(wv, xb.w, acc[7]);
            acc[8] = fmaf(wv, xc.x, acc[8]);  acc[9] = fmaf(wv, xc.y, acc[9]);
            acc[10] = fmaf(wv, xc.z, acc[10]); acc[11] = fmaf(wv, xc.w, acc[11]);
            acc[12] = fmaf(wv, xd.x, acc[12]); acc[13] = fmaf(wv, xd.y, acc[13]);
            acc[14] = fmaf(wv, xd.z, acc[14]); acc[15] = fmaf(wv, xd.w, acc[15]);
        }
        #pragma unroll
        for (int bb = 0; bb < 16; ++bb) gbuf[bb][g] = acc[bb];
    }
    __syncthreads();
    for (int idx = tid; idx < 2400; idx += 640) {
        int j = idx >> 4, bb = idx & 15;
        float ig = gbuf[bb][j]       + bias[j];
        float gg = gbuf[bb][j + 300] + bias[j + 300];
        float og = gbuf[bb][j + 450] + bias[j + 450];
        float cn = sigm(ig) * tanh_(gg);           // c0 = 0 -> forget term vanishes
        float hn = sigm(og) * tanh_(cn);
        net[(size_t)(b0 + bb) * 300 + 150 + j] = hn;
    }
}

// waveform_feat + pef + pef_logits + feat
__global__ void head1(const float* __restrict__ net, const float* __restrict__ rrs,
                      const float* __restrict__ headW, const float* __restrict__ headb,
                      const float* __restrict__ p1W, const float* __restrict__ p1b,
                      const float* __restrict__ p2W, const float* __restrict__ p2b,
                      float* __restrict__ out)
{
    int gid = blockIdx.x * 256 + threadIdx.x;     // 4096
    int b = gid >> 2, og = gid & 3;
    float acc[5];
    #pragma unroll
    for (int o2 = 0; o2 < 5; ++o2) acc[o2] = headb[og * 5 + o2];
    const float* nb = net + (size_t)b * 300;
    for (int k = 0; k < 300; ++k) {
        float nv = nb[k];
        #pragma unroll
        for (int o2 = 0; o2 < 5; ++o2)
            acc[o2] = fmaf(headW[(og * 5 + o2) * 300 + k], nv, acc[o2]);
    }
    #pragma unroll
    for (int o2 = 0; o2 < 5; ++o2) {
        int o = og * 5 + o2;
        float vv = acc[o2] > 0.f ? acc[o2] : 0.3f * acc[o2];
        out[b * 20 + o] = vv;                  // waveform_feat
        out[22528 + b * 30 + o] = vv;          // feat[:, :20]
    }
    if (og == 0) {
        float p[10];
        #pragma unroll
        for (int r = 0; r < 10; ++r) {
            float a = p1b[r];
            #pragma unroll
            for (int qq = 0; qq < 4; ++qq) a = fmaf(p1W[r * 4 + qq], rrs[b * 4 + qq], a);
            p[r] = a > 0.f ? a : 0.3f * a;
            out[22528 + b * 30 + 20 + r] = p[r];   // feat[:, 20:30]
        }
        #pragma unroll
        for (int s = 0; s < 2; ++s) {
            float a = p2b[s];
            #pragma unroll
            for (int r = 0; r < 10; ++r) a = fmaf(p2W[s * 10 + r], p[r], a);
            out[20480 + b * 2 + s] = a;            // pef_logits
        }
    }
}

__global__ void head2(const float* __restrict__ fcW, const float* __restrict__ fcb,
                      float* __restrict__ out)
{
    int b = blockIdx.x * 256 + threadIdx.x;   // 1024
    const float* feat = out + 22528 + b * 30;
    float f[30];
    #pragma unroll
    for (int k = 0; k < 30; ++k) f[k] = feat[k];
    #pragma unroll
    for (int s = 0; s < 4; ++s) {
        float a = fcb[s];
        #pragma unroll
        for (int k = 0; k < 30; ++k) a = fmaf(fcW[s * 30 + k], f[k], a);
        out[53248 + b * 4 + s] = a;
    }
}

extern "C" void kernel_launch(void* const* d_in, const int* in_sizes, int n_in,
                              void* d_out, int out_size, void* d_ws, size_t ws_size,
                              hipStream_t stream)
{
    const float* x     = (const float*)d_in[0];
    const float* rrs   = (const float*)d_in[1];
    const float* W1ihF = (const float*)d_in[2];
    const float* W1hhF = (const float*)d_in[3];
    const float* b1F   = (const float*)d_in[4];
    const float* W1ihB = (const float*)d_in[5];
    const float* W1hhB = (const float*)d_in[6];
    const float* b1B   = (const float*)d_in[7];
    const float* W2ihF = (const float*)d_in[8];
    const float* W2hhF = (const float*)d_in[9];
    const float* b2F   = (const float*)d_in[10];
    const float* W2ihB = (const float*)d_in[11];
    // d_in[12] (l2_Whh_b) unused: backward output at t=T-1 starts from h0=0.
    const float* b2B   = (const float*)d_in[13];
    const float* headW = (const float*)d_in[14];
    const float* headb = (const float*)d_in[15];
    const float* p1W   = (const float*)d_in[16];
    const float* p1b   = (const float*)d_in[17];
    const float* p2W   = (const float*)d_in[18];
    const float* p2b   = (const float*)d_in[19];
    const float* fcW   = (const float*)d_in[20];
    const float* fcb   = (const float*)d_in[21];
    float* out = (float*)d_out;

    char* ws = (char*)d_ws;
    uint4* frag1f = (uint4*)(ws + 0);          //  32 KB (16 tiles x 2 kt)
    uint4* frag1b = (uint4*)(ws + 32768);      //  32 KB
    uint4* frag2f = (uint4*)(ws + 65536);      // 320 KB (40 tiles x 8 kt)
    float* WtT    = (float*)(ws + 393216);     // 240 KB (Wih2_b^T [100][600])
    u16*   out1f  = (u16*)(ws + 655360);       //  32 MB ([128][64][4][64][8] u16)
    float* net    = (float*)(ws + 655360 + 33554432);  // 1.2 MB ([1024][300])
    (void)ws_size; (void)in_sizes; (void)n_in; (void)out_size;

    // GR NW NP KT x_off x_len h_off h_len bias_k
    prep_frag<<<32, 64, 0, stream>>>(W1ihF, W1hhF, b1F, frag1f, 50, 4, 4, 2, 0, 1, 1, 50, 63);
    prep_frag<<<32, 64, 0, stream>>>(W1ihB, W1hhB, b1B, frag1b, 50, 4, 4, 2, 0, 1, 1, 50, 63);
    prep_frag<<<320, 64, 0, stream>>>(W2ihF, W2hhF, b2F, frag2f, 150, 8, 5, 8, 0, 100, 100, 150, 255);
    prep_transT<<<(60000 + 255) / 256, 256, 0, stream>>>(W2ihB, WtT, 100, 600);
    l1_scan<<<dim3(64, 2), 256, 0, stream>>>(x, frag1f, frag1b, out1f);
    l2f_scan<<<64, 512, 0, stream>>>(frag2f, out1f, net);
    l2b_step<<<64, 640, 0, stream>>>(out1f, WtT, b2B, net);
    head1<<<16, 256, 0, stream>>>(net, rrs, headW, headb, p1W, p1b, p2W, p2b, out);
    head2<<<4, 256, 0, stream>>>(fcW, fcb, out);
}

// Round 4
// 295.429 us; speedup vs baseline: 1.9204x; 1.0907x over previous
//
#include <hip/hip_runtime.h>

// BiLSTM on MI355X.
//  - l1_scan: H=50 bidir LSTM, 8 waves x 2 tiles, gates in-register (permuted
//    MFMA weight packing); writes out1 directly in MFMA B-fragment fp16 layout.
//  - l2f_scan: H=150 forward scan; x-fragments streamed from global (prefetch
//    1 step ahead, consumed from registers incl. OR-merge into kt3), h through
//    double-buffered LDS; ONE raw barrier per step (counted waitcnt — global
//    loads/stores stay in flight across the barrier; __syncthreads would drain
//    vmcnt(0) every step = the round-3 stall).
//  - l2b: backward scan's last output = single step from zero state.
//  - bias folded as an extra K-column against a constant-1.0 B row.

typedef unsigned short u16;
typedef unsigned int u32;
typedef float f32x4 __attribute__((ext_vector_type(4)));
typedef _Float16 f16x8 __attribute__((ext_vector_type(8)));
typedef short s16x8 __attribute__((ext_vector_type(8)));

#if __has_builtin(__builtin_amdgcn_mfma_f32_16x16x32_f16)
#define USE_F16 1
#else
#define USE_F16 0
#endif

#define B1 1024
#define TT 128

__device__ __forceinline__ u16 to_h(float x) {
#if USE_F16
    _Float16 h = (_Float16)x;
    return __builtin_bit_cast(u16, h);
#else
    u32 u = __builtin_bit_cast(u32, x);
    u32 r = u + 0x7FFFu + ((u >> 16) & 1u);
    return (u16)(r >> 16);
#endif
}
__device__ __forceinline__ float from_h(u16 s) {
#if USE_F16
    return (float)__builtin_bit_cast(_Float16, s);
#else
    u32 u = ((u32)s) << 16;
    return __builtin_bit_cast(float, u);
#endif
}

__device__ __forceinline__ f32x4 mfma16(uint4 a, uint4 b, f32x4 c) {
#if USE_F16
    return __builtin_amdgcn_mfma_f32_16x16x32_f16(
        __builtin_bit_cast(f16x8, a), __builtin_bit_cast(f16x8, b), c, 0, 0, 0);
#else
    return __builtin_amdgcn_mfma_f32_16x16x32_bf16(
        __builtin_bit_cast(s16x8, a), __builtin_bit_cast(s16x8, b), c, 0, 0, 0);
#endif
}

#define LOG2E 1.4426950408889634f
__device__ __forceinline__ float sigm(float x) {
    return __builtin_amdgcn_rcpf(1.f + __builtin_amdgcn_exp2f(-LOG2E * x));
}
__device__ __forceinline__ float tanh_(float x) {
    return 1.f - 2.f * __builtin_amdgcn_rcpf(1.f + __builtin_amdgcn_exp2f(2.f * LOG2E * x));
}

// Raw workgroup barrier: waits only LDS ops (lgkmcnt), leaves global loads/
// stores in flight (compiler inserts counted vmcnt before register uses).
__device__ __forceinline__ void wg_barrier_lds() {
    __builtin_amdgcn_sched_barrier(0);
    asm volatile("s_waitcnt lgkmcnt(0)" ::: "memory");
    __builtin_amdgcn_s_barrier();
    __builtin_amdgcn_sched_barrier(0);
}

// ---------------------------------------------------------------------------
// Weight packing [Wih | Whh | bias-col | 0] into MFMA A-fragments with the
// gate permutation: tile = w + NW*p, row-in-tile = q*4 + tau,
// group jj = (w*4+q)*NP + p, original weight row = tau*GR + jj.
__device__ __forceinline__ void prep_frag_body(
    const float* __restrict__ Wih, const float* __restrict__ Whh,
    const float* __restrict__ bias, uint4* __restrict__ dst,
    int GR, int NW, int NP, int KT,
    int x_off, int x_len, int h_off, int h_len, int bias_k, int bid, int l)
{
    int tile = bid / KT, kt = bid - tile * KT;
    int ml = l & 15;
    int qq = ml >> 2, tau = ml & 3;
    int w = tile % NW, p = tile / NW;
    int jj = (w * 4 + qq) * NP + p;
    bool valid = jj < GR;
    int row = tau * GR + jj;
    u32 dw[4];
    #pragma unroll
    for (int d = 0; d < 4; ++d) {
        u16 hh[2];
        #pragma unroll
        for (int s = 0; s < 2; ++s) {
            int j = d * 2 + s;
            int k = kt * 32 + (l >> 4) * 8 + j;
            float val = 0.f;
            if (valid) {
                if (k >= x_off && k < x_off + x_len) val = Wih[row * x_len + (k - x_off)];
                else if (k >= h_off && k < h_off + h_len) val = Whh[row * h_len + (k - h_off)];
                else if (k == bias_k) val = bias[row];
            }
            hh[s] = to_h(val);
        }
        dw[d] = (u32)hh[0] | ((u32)hh[1] << 16);
    }
    uint4 o; o.x = dw[0]; o.y = dw[1]; o.z = dw[2]; o.w = dw[3];
    dst[bid * 64 + l] = o;
}

__global__ void prep_all(const float* __restrict__ W1ihF, const float* __restrict__ W1hhF,
                         const float* __restrict__ b1F,
                         const float* __restrict__ W1ihB, const float* __restrict__ W1hhB,
                         const float* __restrict__ b1B,
                         const float* __restrict__ W2ihF, const float* __restrict__ W2hhF,
                         const float* __restrict__ b2F, const float* __restrict__ W2ihB,
                         uint4* __restrict__ frag1f, uint4* __restrict__ frag1b,
                         uint4* __restrict__ frag2f, float* __restrict__ WtT)
{
    int bid = blockIdx.x;
    int l = threadIdx.x;
    if (bid < 32)
        prep_frag_body(W1ihF, W1hhF, b1F, frag1f, 50, 8, 2, 2, 0, 1, 1, 50, 63, bid, l);
    else if (bid < 64)
        prep_frag_body(W1ihB, W1hhB, b1B, frag1b, 50, 8, 2, 2, 0, 1, 1, 50, 63, bid - 32, l);
    else if (bid < 384)
        prep_frag_body(W2ihF, W2hhF, b2F, frag2f, 150, 8, 5, 8, 0, 100, 100, 150, 255, bid - 64, l);
    else {
        int idx = (bid - 384) * 64 + l;          // WtT[k][g] = W2ihB[g][k]
        if (idx < 60000) {
            int k = idx / 600, g = idx - k * 600;
            WtT[idx] = W2ihB[g * 100 + k];
        }
    }
}

// ---------------------------------------------------------------------------
// Layer 1: K=64 (x k=0, h k=1..50, bias k=63). 512 thr = 8 waves, 2 tiles/wave
// (tile = w+8p), groups jj = (w*4+q)*2+p (valid < 50).
// out1f layout: u16 fragment tensor [t][blk16][ktx(4)][lane(64)][e(8)].
__global__ __launch_bounds__(512, 2) void l1_scan(
    const float* __restrict__ x, const uint4* __restrict__ fragF,
    const uint4* __restrict__ fragB, u16* __restrict__ out1f)
{
    const int tid = threadIdx.x;
    const int lane = tid & 63;
    const int w = tid >> 6;
    const int q = lane >> 4;
    const int b = lane & 15;
    const int blk = blockIdx.x;
    const int dir = blockIdx.y;
    const uint4* frag = dir ? fragB : fragF;

    __shared__ u16 v[2][1024];        // [buf][kt(2)*64 lanes*8 e]
    __shared__ float x_s[128][17];    // padded: conflict-free col reads

    uint4 af[2][2];
    #pragma unroll
    for (int i = 0; i < 2; ++i)
        #pragma unroll
        for (int kt = 0; kt < 2; ++kt)
            af[i][kt] = frag[((w + 8 * i) * 2 + kt) * 64 + lane];

    const int b0 = blk * 16;
    for (int idx = tid; idx < 1024; idx += 512) ((u32*)v)[idx] = 0u;
    for (int idx = tid; idx < 2048; idx += 512) {
        int bb = idx >> 7, t = idx & 127;
        x_s[t][bb] = x[(size_t)(b0 + bb) * TT + t];
    }
    __syncthreads();                  // zero-init complete before special slots
    const u16 oneh = to_h(1.0f);
    if (tid < 16) {
        v[0][(112 + tid) * 8 + 7] = oneh;             // bias row k=63, both bufs
        v[1][(112 + tid) * 8 + 7] = oneh;
        v[0][tid * 8] = to_h(x[(size_t)(b0 + tid) * TT + (dir ? TT - 1 : 0)]);
    }
    const int jjb = (w * 4 + q) * 2;
    int vslot[2]; size_t eb[2];
    #pragma unroll
    for (int p = 0; p < 2; ++p) {
        int jj = jjb + p;
        int k = 1 + jj;
        vslot[p] = ((k >> 5) * 64 + ((k & 31) >> 3) * 16 + b) * 8 + (k & 7);
        int k2 = dir * 50 + jj;
        eb[p] = (((size_t)blk * 4 + (k2 >> 5)) * 64 + ((k2 & 31) >> 3) * 16 + b) * 8 + (k2 & 7);
    }
    float c[2] = {0.f, 0.f};
    __syncthreads();

#define L1_STEP(T, CUR) { \
    uint4 bf0 = *(const uint4*)&v[CUR][lane * 8]; \
    uint4 bf1 = *(const uint4*)&v[CUR][(64 + lane) * 8]; \
    f32x4 acc[2]; \
    _Pragma("unroll") for (int i = 0; i < 2; ++i) acc[i] = (f32x4){0.f, 0.f, 0.f, 0.f}; \
    _Pragma("unroll") for (int i = 0; i < 2; ++i) acc[i] = mfma16(af[i][0], bf0, acc[i]); \
    _Pragma("unroll") for (int i = 0; i < 2; ++i) acc[i] = mfma16(af[i][1], bf1, acc[i]); \
    const int tt = dir ? 127 - (T) : (T); \
    _Pragma("unroll") for (int p = 0; p < 2; ++p) { \
        if (jjb + p < 50) { \
            float ig = acc[p][0], fg = acc[p][1], gg = acc[p][2], og = acc[p][3]; \
            float cn = sigm(fg) * c[p] + sigm(ig) * tanh_(gg); \
            float hn = sigm(og) * tanh_(cn); \
            c[p] = cn; \
            u16 hb = to_h(hn); \
            out1f[eb[p] + (size_t)tt * 131072] = hb; \
            v[1 - (CUR)][vslot[p]] = hb; \
        } \
    } \
    if (tid < 16 && (T) < 127) \
        v[1 - (CUR)][tid * 8] = to_h(x_s[dir ? 126 - (T) : (T) + 1][tid]); \
    wg_barrier_lds(); }

    for (int t2 = 0; t2 < TT; t2 += 2) {
        L1_STEP(t2, 0)
        L1_STEP(t2 + 1, 1)
    }
#undef L1_STEP
}

// ---------------------------------------------------------------------------
// Layer 2 forward: K=256 (x k=0..99, h k=100..249, bias k=255). 512 thr = 8
// waves, 5 tiles/wave (tile = w+8p), groups jj = (w*4+q)*5+p (valid < 150).
// x kt0..2 MFMA'd from prefetch regs; x k=96..99 OR-merged (masked) into the
// kt3 LDS operand whose those slots are permanently zero. h double-buffered in
// LDS. ONE raw barrier per step; global loads stay in flight across it.
__global__ __launch_bounds__(512, 2) void l2f_scan(
    const uint4* __restrict__ frag, const u16* __restrict__ out1f,
    float* __restrict__ net)
{
    const int tid = threadIdx.x;
    const int lane = tid & 63;
    const int w = tid >> 6;
    const int q = lane >> 4;
    const int b = lane & 15;
    const int blk = blockIdx.x;
    const int b0 = blk * 16;
    const uint4* o4 = (const uint4*)out1f;

    __shared__ u16 v[2][4096];        // [buf][kt(8)*64 lanes*8 e]

    uint4 af[5][8];
    #pragma unroll
    for (int i = 0; i < 5; ++i)
        #pragma unroll
        for (int kt = 0; kt < 8; ++kt)
            af[i][kt] = frag[((w + 8 * i) * 8 + kt) * 64 + lane];

    for (int idx = tid; idx < 4096; idx += 512) ((u32*)v)[idx] = 0u;

    uint4 pfA[4], pfB[4];
    #pragma unroll
    for (int ktx = 0; ktx < 4; ++ktx)
        pfA[ktx] = o4[((size_t)blk * 4 + ktx) * 64 + lane];

    __syncthreads();                  // zero-init complete before special slots
    const u16 oneh = to_h(1.0f);
    if (tid < 16) {                   // bias row k=255, both bufs
        v[0][(496 + tid) * 8 + 7] = oneh;
        v[1][(496 + tid) * 8 + 7] = oneh;
    }

    const u32 umask = (q == 0) ? 0xFFFFFFFFu : 0u;   // x k=96..99 live in q==0,e0..3
    const int jjb = (w * 4 + q) * 5;
    int vslot[5];
    #pragma unroll
    for (int p = 0; p < 5; ++p) {
        int k = 100 + jjb + p;
        vslot[p] = ((k >> 5) * 64 + ((k & 31) >> 3) * 16 + b) * 8 + (k & 7);
    }
    float c[5] = {0.f, 0.f, 0.f, 0.f, 0.f};
    __syncthreads();

#define L2F_STEP(T, CUR, PFC, PFN) { \
    const int tn = ((T) < 127) ? (T) + 1 : 127; \
    _Pragma("unroll") for (int ktx = 0; ktx < 4; ++ktx) \
        PFN[ktx] = o4[(((size_t)tn * 64 + blk) * 4 + ktx) * 64 + lane]; \
    uint4 bfu[5]; \
    _Pragma("unroll") for (int kh = 0; kh < 5; ++kh) \
        bfu[kh] = *(const uint4*)&v[CUR][((kh + 3) * 64 + lane) * 8]; \
    bfu[0].x |= PFC[3].x & umask; \
    bfu[0].y |= PFC[3].y & umask; \
    f32x4 acc[5]; \
    _Pragma("unroll") for (int i = 0; i < 5; ++i) acc[i] = (f32x4){0.f, 0.f, 0.f, 0.f}; \
    _Pragma("unroll") for (int kt = 0; kt < 3; ++kt) { \
        _Pragma("unroll") for (int i = 0; i < 5; ++i) \
            acc[i] = mfma16(af[i][kt], PFC[kt], acc[i]); } \
    _Pragma("unroll") for (int kh = 0; kh < 5; ++kh) { \
        _Pragma("unroll") for (int i = 0; i < 5; ++i) \
            acc[i] = mfma16(af[i][kh + 3], bfu[kh], acc[i]); } \
    _Pragma("unroll") for (int p = 0; p < 5; ++p) { \
        float ig = acc[p][0], fg = acc[p][1], gg = acc[p][2], og = acc[p][3]; \
        float cn = sigm(fg) * c[p] + sigm(ig) * tanh_(gg); \
        float hn = sigm(og) * tanh_(cn); \
        c[p] = cn; \
        if (jjb + p < 150) { \
            v[1 - (CUR)][vslot[p]] = to_h(hn); \
            if ((T) == 127) net[(size_t)(b0 + b) * 300 + jjb + p] = hn; \
        } \
    } \
    wg_barrier_lds(); }

    for (int t2 = 0; t2 < TT; t2 += 2) {
        L2F_STEP(t2, 0, pfA, pfB)
        L2F_STEP(t2 + 1, 1, pfB, pfA)
    }
#undef L2F_STEP
}

// ---------------------------------------------------------------------------
// Layer 2 backward = single step from zero state (Whh_b drops out).
__global__ __launch_bounds__(640, 1) void l2b_step(
    const u16* __restrict__ out1f, const float* __restrict__ WtT,
    const float* __restrict__ bias, float* __restrict__ net)   // writes [:, 150:300]
{
    const int tid = threadIdx.x;
    const int blk = blockIdx.x;
    const int b0 = blk * 16;
    __shared__ alignas(16) float x_s[100][16];
    __shared__ alignas(16) float gbuf[16][644];
    for (int idx = tid; idx < 1600; idx += 640) {
        int k2 = idx >> 4, bb = idx & 15;
        x_s[k2][bb] = from_h(out1f[((((size_t)127 * 64 + blk) * 4 + (k2 >> 5)) * 64
                                    + ((k2 & 31) >> 3) * 16 + bb) * 8 + (k2 & 7)]);
    }
    __syncthreads();
    if (tid < 600) {
        int g = tid;
        float acc[16];
        #pragma unroll
        for (int bb = 0; bb < 16; ++bb) acc[bb] = 0.f;
        for (int k = 0; k < 100; ++k) {
            float wv = WtT[k * 600 + g];
            float4 xa = *(const float4*)&x_s[k][0];
            float4 xb = *(const float4*)&x_s[k][4];
            float4 xc = *(const float4*)&x_s[k][8];
            float4 xd = *(const float4*)&x_s[k][12];
            acc[0] = fmaf(wv, xa.x, acc[0]);  acc[1] = fmaf(wv, xa.y, acc[1]);
            acc[2] = fmaf(wv, xa.z, acc[2]);  acc[3] = fmaf(wv, xa.w, acc[3]);
            acc[4] = fmaf(wv, xb.x, acc[4]);  acc[5] = fmaf(wv, xb.y, acc[5]);
            acc[6] = fmaf(wv, xb.z, acc[6]);  acc[7] = fmaf(wv, xb.w, acc[7]);
            acc[8] = fmaf(wv, xc.x, acc[8]);  acc[9] = fmaf(wv, xc.y, acc[9]);
            acc[10] = fmaf(wv, xc.z, acc[10]); acc[11] = fmaf(wv, xc.w, acc[11]);
            acc[12] = fmaf(wv, xd.x, acc[12]); acc[13] = fmaf(wv, xd.y, acc[13]);
            acc[14] = fmaf(wv, xd.z, acc[14]); acc[15] = fmaf(wv, xd.w, acc[15]);
        }
        #pragma unroll
        for (int bb = 0; bb < 16; ++bb) gbuf[bb][g] = acc[bb];
    }
    __syncthreads();
    for (int idx = tid; idx < 2400; idx += 640) {
        int j = idx >> 4, bb = idx & 15;
        float ig = gbuf[bb][j]       + bias[j];
        float gg = gbuf[bb][j + 300] + bias[j + 300];
        float og = gbuf[bb][j + 450] + bias[j + 450];
        float cn = sigm(ig) * tanh_(gg);           // c0 = 0 -> forget term vanishes
        float hn = sigm(og) * tanh_(cn);
        net[(size_t)(b0 + bb) * 300 + 150 + j] = hn;
    }
}

// waveform_feat + pef + pef_logits + feat
__global__ void head1(const float* __restrict__ net, const float* __restrict__ rrs,
                      const float* __restrict__ headW, const float* __restrict__ headb,
                      const float* __restrict__ p1W, const float* __restrict__ p1b,
                      const float* __restrict__ p2W, const float* __restrict__ p2b,
                      float* __restrict__ out)
{
    int gid = blockIdx.x * 256 + threadIdx.x;     // 4096
    int b = gid >> 2, og = gid & 3;
    float acc[5];
    #pragma unroll
    for (int o2 = 0; o2 < 5; ++o2) acc[o2] = headb[og * 5 + o2];
    const float* nb = net + (size_t)b * 300;
    for (int k = 0; k < 300; ++k) {
        float nv = nb[k];
        #pragma unroll
        for (int o2 = 0; o2 < 5; ++o2)
            acc[o2] = fmaf(headW[(og * 5 + o2) * 300 + k], nv, acc[o2]);
    }
    #pragma unroll
    for (int o2 = 0; o2 < 5; ++o2) {
        int o = og * 5 + o2;
        float vv = acc[o2] > 0.f ? acc[o2] : 0.3f * acc[o2];
        out[b * 20 + o] = vv;                  // waveform_feat
        out[22528 + b * 30 + o] = vv;          // feat[:, :20]
    }
    if (og == 0) {
        float p[10];
        #pragma unroll
        for (int r = 0; r < 10; ++r) {
            float a = p1b[r];
            #pragma unroll
            for (int qq = 0; qq < 4; ++qq) a = fmaf(p1W[r * 4 + qq], rrs[b * 4 + qq], a);
            p[r] = a > 0.f ? a : 0.3f * a;
            out[22528 + b * 30 + 20 + r] = p[r];   // feat[:, 20:30]
        }
        #pragma unroll
        for (int s = 0; s < 2; ++s) {
            float a = p2b[s];
            #pragma unroll
            for (int r = 0; r < 10; ++r) a = fmaf(p2W[s * 10 + r], p[r], a);
            out[20480 + b * 2 + s] = a;            // pef_logits
        }
    }
}

__global__ void head2(const float* __restrict__ fcW, const float* __restrict__ fcb,
                      float* __restrict__ out)
{
    int b = blockIdx.x * 256 + threadIdx.x;   // 1024
    const float* feat = out + 22528 + b * 30;
    float f[30];
    #pragma unroll
    for (int k = 0; k < 30; ++k) f[k] = feat[k];
    #pragma unroll
    for (int s = 0; s < 4; ++s) {
        float a = fcb[s];
        #pragma unroll
        for (int k = 0; k < 30; ++k) a = fmaf(fcW[s * 30 + k], f[k], a);
        out[53248 + b * 4 + s] = a;
    }
}

extern "C" void kernel_launch(void* const* d_in, const int* in_sizes, int n_in,
                              void* d_out, int out_size, void* d_ws, size_t ws_size,
                              hipStream_t stream)
{
    const float* x     = (const float*)d_in[0];
    const float* rrs   = (const float*)d_in[1];
    const float* W1ihF = (const float*)d_in[2];
    const float* W1hhF = (const float*)d_in[3];
    const float* b1F   = (const float*)d_in[4];
    const float* W1ihB = (const float*)d_in[5];
    const float* W1hhB = (const float*)d_in[6];
    const float* b1B   = (const float*)d_in[7];
    const float* W2ihF = (const float*)d_in[8];
    const float* W2hhF = (const float*)d_in[9];
    const float* b2F   = (const float*)d_in[10];
    const float* W2ihB = (const float*)d_in[11];
    // d_in[12] (l2_Whh_b) unused: backward output at t=T-1 starts from h0=0.
    const float* b2B   = (const float*)d_in[13];
    const float* headW = (const float*)d_in[14];
    const float* headb = (const float*)d_in[15];
    const float* p1W   = (const float*)d_in[16];
    const float* p1b   = (const float*)d_in[17];
    const float* p2W   = (const float*)d_in[18];
    const float* p2b   = (const float*)d_in[19];
    const float* fcW   = (const float*)d_in[20];
    const float* fcb   = (const float*)d_in[21];
    float* out = (float*)d_out;

    char* ws = (char*)d_ws;
    uint4* frag1f = (uint4*)(ws + 0);          //  32 KB (16 tiles x 2 kt)
    uint4* frag1b = (uint4*)(ws + 32768);      //  32 KB
    uint4* frag2f = (uint4*)(ws + 65536);      // 320 KB (40 tiles x 8 kt)
    float* WtT    = (float*)(ws + 393216);     // 240 KB (Wih2_b^T [100][600])
    u16*   out1f  = (u16*)(ws + 655360);       //  32 MB ([128][64][4][64][8] u16)
    float* net    = (float*)(ws + 655360 + 33554432);  // 1.2 MB ([1024][300])
    (void)ws_size; (void)in_sizes; (void)n_in; (void)out_size;

    prep_all<<<1322, 64, 0, stream>>>(W1ihF, W1hhF, b1F, W1ihB, W1hhB, b1B,
                                      W2ihF, W2hhF, b2F, W2ihB,
                                      frag1f, frag1b, frag2f, WtT);
    l1_scan<<<dim3(64, 2), 512, 0, stream>>>(x, frag1f, frag1b, out1f);
    l2f_scan<<<64, 512, 0, stream>>>(frag2f, out1f, net);
    l2b_step<<<64, 640, 0, stream>>>(out1f, WtT, b2B, net);
    head1<<<16, 256, 0, stream>>>(net, rrs, headW, headb, p1W, p1b, p2W, p2b, out);
    head2<<<4, 256, 0, stream>>>(fcW, fcb, out);
}